// Round 6
// baseline (477.245 us; speedup 1.0000x reference)
//
#include <hip/hip_runtime.h>

// Subtractor50Bit: A - B via two's complement, N rows x 50 bits ({0,1} floats).
// out = [result (N*50 floats), borrow (N floats)].
//
// R5 = R4 + fence-ordered LDS phases. R4's wave-synchronous LDS (write ->
// cross-lane read with NO barrier/fence, mixed float4/float2 access types)
// let the compiler reorder/elide across the phases (cross-lane data flow is
// invisible to per-lane alias analysis) -> bit garbage. Fix: clamp the tile
// index so all threads reach barriers, and __syncthreads() at every LDS
// phase boundary (fence orders all memory regardless of aliasing metadata).
//
// Structure: one wave per 64-row tile, wave-private 12.8KB LDS slab:
//   1) all 26 coalesced float4 loads (A+B) issued together (full MLP)
//   2) stage A in LDS | bar | each lane packs its own row (50 floats) into a
//      50-bit int via (as_uint(f) >> 29) & 1   (1.0f=0x3F800000 -> bit29=1)
//   3) bar | stage B | bar | pack bv; 64-bit subtract -> sum bits + borrow
//   4) bar | unpack bits to floats in LDS | bar | coalesced float4 store

constexpr int BITS = 50;
constexpr unsigned long long MASK50 = (1ULL << BITS) - 1ULL;
constexpr int TR = 64;               // rows per tile (one wave)
constexpr int TE = TR * BITS;        // 3200 floats per tile

__global__ __launch_bounds__(256, 3) void Subtractor50Bit_kernel(
    const float* __restrict__ A, const float* __restrict__ B,
    float* __restrict__ out, int N, int numTiles)
{
    __shared__ float buf[4][TE];     // 51.2 KB/block -> 3 blocks/CU (LDS-limited)
    const int lane = threadIdx.x & 63;
    const int wv   = threadIdx.x >> 6;

    // scalar tail for N % 64 leftover rows (none for N = 1e6; safety net)
    if (blockIdx.x == 0 && threadIdx.x < 64) {
        long long r = (long long)numTiles * TR + lane;
        if (r < N) {
            unsigned long long av = 0, bv = 0;
            for (int k = 0; k < BITS; ++k) {
                av |= (unsigned long long)(A[r * BITS + k] != 0.0f) << k;
                bv |= (unsigned long long)(B[r * BITS + k] != 0.0f) << k;
            }
            unsigned long long d = (av - bv) & MASK50;
            for (int k = 0; k < BITS; ++k)
                out[r * BITS + k] = (float)((d >> k) & 1ULL);
            out[(long long)N * BITS + r] = (av < bv) ? 1.0f : 0.0f;
        }
    }

    if (numTiles <= 0) return;   // grid-uniform; no barrier divergence

    // Clamp instead of early-return so EVERY thread reaches the barriers.
    // Clamped waves redo the last tile (duplicate identical global writes:
    // benign) in their own private LDS slab.
    long long t = (long long)blockIdx.x * 4 + wv;
    if (t >= numTiles) t = numTiles - 1;

    float* S = buf[wv];
    float4* S4 = (float4*)S;
    float2* S2t = (float2*)(S + 3072);           // tail 128 floats of the tile
    const long long eBase = t * (long long)TE;

    // ---- Phase 1: issue ALL global loads (A and B) — independent, coalesced.
    float4 ra[12], rb[12];
    float2 ra2, rb2;
    {
        const float4* a4 = (const float4*)(A + eBase);
        const float4* b4 = (const float4*)(B + eBase);
        #pragma unroll
        for (int k = 0; k < 12; ++k) {
            ra[k] = a4[k * 64 + lane];
            rb[k] = b4[k * 64 + lane];
        }
        ra2 = ((const float2*)(A + eBase + 3072))[lane];
        rb2 = ((const float2*)(B + eBase + 3072))[lane];
    }

    // ---- Phase 2: stage A | bar | pack my row (50 floats at 50*lane).
    #pragma unroll
    for (int k = 0; k < 12; ++k) S4[k * 64 + lane] = ra[k];
    S2t[lane] = ra2;
    __syncthreads();

    unsigned long long av;
    {
        const float2* R = (const float2*)(S + BITS * lane);  // 8B-aligned
        unsigned int lo = 0, hi = 0;
        #pragma unroll
        for (int k = 0; k < 25; ++k) {
            float2 v = R[k];
            unsigned int b0 = (__float_as_uint(v.x) >> 29) & 1u;  // 1.0f -> 1
            unsigned int b1 = (__float_as_uint(v.y) >> 29) & 1u;
            const int j = 2 * k;
            if (j < 32)     lo |= b0 << j;        else hi |= b0 << (j - 32);
            if (j + 1 < 32) lo |= b1 << (j + 1);  else hi |= b1 << (j + 1 - 32);
        }
        av = ((unsigned long long)hi << 32) | lo;
    }
    __syncthreads();   // WAR: all lanes done reading A before B overwrites

    // ---- Phase 3: stage B | bar | pack bv.
    #pragma unroll
    for (int k = 0; k < 12; ++k) S4[k * 64 + lane] = rb[k];
    S2t[lane] = rb2;
    __syncthreads();

    unsigned long long bv;
    {
        const float2* R = (const float2*)(S + BITS * lane);
        unsigned int lo = 0, hi = 0;
        #pragma unroll
        for (int k = 0; k < 25; ++k) {
            float2 v = R[k];
            unsigned int b0 = (__float_as_uint(v.x) >> 29) & 1u;
            unsigned int b1 = (__float_as_uint(v.y) >> 29) & 1u;
            const int j = 2 * k;
            if (j < 32)     lo |= b0 << j;        else hi |= b0 << (j - 32);
            if (j + 1 < 32) lo |= b1 << (j + 1);  else hi |= b1 << (j + 1 - 32);
        }
        bv = ((unsigned long long)hi << 32) | lo;
    }
    __syncthreads();   // WAR: all lanes done reading B before unpack writes

    // ---- Phase 4: integer subtract == ripple-carry A + ~B + 1.
    const unsigned long long diff = (av - bv) & MASK50;   // sum bits
    const float borrow = (av < bv) ? 1.0f : 0.0f;         // 1 - carry_out
    const unsigned int dlo = (unsigned int)diff;
    const unsigned int dhi = (unsigned int)(diff >> 32);

    // ---- Phase 5: unpack my row's bits to floats | bar | coalesced store.
    {
        float2* W = (float2*)(S + BITS * lane);
        #pragma unroll
        for (int k = 0; k < 25; ++k) {
            const int j = 2 * k;
            unsigned int b0 = ((j < 32) ? (dlo >> j) : (dhi >> (j - 32))) & 1u;
            unsigned int b1 = ((j + 1 < 32) ? (dlo >> (j + 1)) : (dhi >> (j + 1 - 32))) & 1u;
            W[k] = make_float2((float)b0, (float)b1);
        }
    }
    __syncthreads();

    {
        float4* o4 = (float4*)(out + eBase);
        #pragma unroll
        for (int k = 0; k < 12; ++k) {
            float4 v = S4[k * 64 + lane];
            o4[k * 64 + lane] = v;
        }
        float2 v2 = S2t[lane];
        ((float2*)(out + eBase + 3072))[lane] = v2;
        out[(long long)N * BITS + t * TR + lane] = borrow;
    }
}

extern "C" void kernel_launch(void* const* d_in, const int* in_sizes, int n_in,
                              void* d_out, int out_size, void* d_ws, size_t ws_size,
                              hipStream_t stream) {
    const float* A = (const float*)d_in[0];
    const float* B = (const float*)d_in[1];
    float* out = (float*)d_out;
    const int N = in_sizes[0] / BITS;           // 1,000,000

    const int numTiles = N / TR;                // 15625 full tiles
    int blocks = (numTiles + 3) / 4;            // 4 waves (tiles) per block
    if (blocks < 1) blocks = 1;
    Subtractor50Bit_kernel<<<blocks, 256, 0, stream>>>(A, B, out, N, numTiles);
}